// Round 2
// baseline (1426.015 us; speedup 1.0000x reference)
//
#include <hip/hip_runtime.h>
#include <hip/hip_bf16.h>

#define NPIX 9216
#define IMH 96
#define IMW 96
#define NC 21
#define CPAD 24
#define CH 192
#define NITER 5
#define PROWS 48

// ---------------- Kernel A: unary conv + initial softmax + features ----------------
__global__ __launch_bounds__(256) void prep_kernel(
    const float* __restrict__ img,
    const float* __restrict__ net_w,
    const float* __restrict__ net_b,
    float* __restrict__ u, float* __restrict__ s, float* __restrict__ feats)
{
    __shared__ float wsh[567];
    __shared__ float bsh[21];
    const int tid = threadIdx.x;
    for (int i = tid; i < 567; i += 256) wsh[i] = net_w[i];
    if (tid < 21) bsh[tid] = net_b[tid];
    __syncthreads();

    const int n = blockIdx.x * 256 + tid;
    const int i = n / IMW, j = n % IMW;

    float acc[NC];
    #pragma unroll
    for (int o = 0; o < NC; o++) acc[o] = bsh[o];

    for (int ci = 0; ci < 3; ci++) {
        for (int ky = 0; ky < 3; ky++) {
            for (int kx = 0; kx < 3; kx++) {
                const int ii = i + ky - 1, jj = j + kx - 1;
                float v = 0.f;
                if (ii >= 0 && ii < IMH && jj >= 0 && jj < IMW)
                    v = img[(ci * IMH + ii) * IMW + jj];
                #pragma unroll
                for (int o = 0; o < NC; o++)
                    acc[o] = fmaf(v, wsh[((o * 3 + ci) * 3 + ky) * 3 + kx], acc[o]);
            }
        }
    }

    float mx = acc[0];
    #pragma unroll
    for (int o = 1; o < NC; o++) mx = fmaxf(mx, acc[o]);
    float e[NC], sum = 0.f;
    #pragma unroll
    for (int o = 0; o < NC; o++) { e[o] = __expf(acc[o] - mx); sum += e[o]; }
    const float inv = 1.f / sum;
    #pragma unroll
    for (int o = 0; o < NC; o++) { u[n * CPAD + o] = acc[o]; s[n * CPAD + o] = e[o] * inv; }
    // column 21 = 1.0 -> filter norm falls out of the class-FMA loop for free
    u[n * CPAD + 21] = 0.f; u[n * CPAD + 22] = 0.f; u[n * CPAD + 23] = 0.f;
    s[n * CPAD + 21] = 1.f; s[n * CPAD + 22] = 0.f; s[n * CPAD + 23] = 0.f;

    const float r = img[0 * NPIX + n];
    const float g = img[1 * NPIX + n];
    const float b = img[2 * NPIX + n];
    feats[n * 8 + 0] = (float)j;  // x
    feats[n * 8 + 1] = (float)i;  // y
    feats[n * 8 + 2] = r;
    feats[n * 8 + 3] = g;
    feats[n * 8 + 4] = b;
    feats[n * 8 + 5] = 0.f; feats[n * 8 + 6] = 0.f; feats[n * 8 + 7] = 0.f;
}

// ---------------- Kernel B: dense spatial + bilateral filtering (partials) ----------------
__global__ __launch_bounds__(256) void filt_kernel(
    const float* __restrict__ s, const float* __restrict__ feats,
    float* __restrict__ P, int chunkLen)
{
    __shared__ float s_sh[CH * CPAD];  // 18 KB
    __shared__ float f_sh[CH * 8];     // 6 KB
    const int tid = threadIdx.x;
    const int n = blockIdx.x * 256 + tid;
    const int mstart = blockIdx.y * chunkLen;

    const float xn = feats[n * 8 + 0];
    const float yn = feats[n * 8 + 1];
    const float rn = feats[n * 8 + 2];
    const float gn = feats[n * 8 + 3];
    const float bn = feats[n * 8 + 4];

    float accS[CPAD], accB[CPAD];
    #pragma unroll
    for (int c = 0; c < CPAD; c++) { accS[c] = 0.f; accB[c] = 0.f; }

    const int nsub = chunkLen / CH;
    for (int sc = 0; sc < nsub; sc++) {
        const int base = mstart + sc * CH;
        const float4* gs = (const float4*)(s + (size_t)base * CPAD);
        float4* ls = (float4*)s_sh;
        for (int i2 = tid; i2 < CH * CPAD / 4; i2 += 256) ls[i2] = gs[i2];
        const float4* gf = (const float4*)(feats + (size_t)base * 8);
        float4* lf = (float4*)f_sh;
        for (int i2 = tid; i2 < CH * 2; i2 += 256) lf[i2] = gf[i2];
        __syncthreads();

        for (int mm = 0; mm < CH; mm++) {
            const float4 f0 = *(const float4*)(f_sh + mm * 8); // x,y,r,g
            const float fb5 = f_sh[mm * 8 + 4];                // b
            const float dx = xn - f0.x, dy = yn - f0.y;
            const float d2p = dx * dx + dy * dy;
            const float dr = rn - f0.z, dg = gn - f0.w, db = bn - fb5;
            const float d2c = dr * dr + dg * dg + db * db;
            // k_sp = exp(-0.5*d2p/gamma^2), gamma=3
            const float ksp = __expf(-0.055555556f * d2p);
            // k_bl = exp(-0.5*(d2p/alpha^2 + d2c/beta^2)), alpha=160, beta=3
            const float kbl = __expf(fmaf(-1.953125e-5f, d2p, -0.055555556f * d2c));
            const float4* srow = (const float4*)(s_sh + mm * CPAD);
            #pragma unroll
            for (int jv = 0; jv < 6; jv++) {
                const float4 sv = srow[jv];
                accS[4 * jv + 0] = fmaf(ksp, sv.x, accS[4 * jv + 0]);
                accS[4 * jv + 1] = fmaf(ksp, sv.y, accS[4 * jv + 1]);
                accS[4 * jv + 2] = fmaf(ksp, sv.z, accS[4 * jv + 2]);
                accS[4 * jv + 3] = fmaf(ksp, sv.w, accS[4 * jv + 3]);
                accB[4 * jv + 0] = fmaf(kbl, sv.x, accB[4 * jv + 0]);
                accB[4 * jv + 1] = fmaf(kbl, sv.y, accB[4 * jv + 1]);
                accB[4 * jv + 2] = fmaf(kbl, sv.z, accB[4 * jv + 2]);
                accB[4 * jv + 3] = fmaf(kbl, sv.w, accB[4 * jv + 3]);
            }
        }
        __syncthreads();
    }

    // P layout: [split][48 rows][NPIX]; rows 0..23 = spatial (21=norm), 24..47 = bilateral (45=norm)
    float* Pp = P + (size_t)blockIdx.y * PROWS * NPIX;
    #pragma unroll
    for (int c = 0; c < CPAD; c++) {
        Pp[c * NPIX + n] = accS[c];
        Pp[(CPAD + c) * NPIX + n] = accB[c];
    }
}

// ---------------- Kernel C: reduce partials + compat transform + softmax ----------------
__global__ __launch_bounds__(256) void combine_kernel(
    const float* __restrict__ P, int msplit,
    const float* __restrict__ u,
    const float* __restrict__ sp_w, const float* __restrict__ sp_b,
    const float* __restrict__ bl_w, const float* __restrict__ bl_b,
    const float* __restrict__ comp_w, const float* __restrict__ comp_b,
    float* __restrict__ s, float* __restrict__ out, int write_out)
{
    __shared__ float spw[441], blw[441], cpw[441], spb[21], blb[21], cpb[21];
    const int tid = threadIdx.x;
    for (int i = tid; i < 441; i += 256) {
        spw[i] = sp_w[i]; blw[i] = bl_w[i]; cpw[i] = comp_w[i];
    }
    if (tid < 21) { spb[tid] = sp_b[tid]; blb[tid] = bl_b[tid]; cpb[tid] = comp_b[tid]; }
    __syncthreads();

    const int n = blockIdx.x * 256 + tid;
    float acc[PROWS];
    #pragma unroll
    for (int r = 0; r < PROWS; r++) acc[r] = 0.f;
    for (int k = 0; k < msplit; k++) {
        const float* Pp = P + (size_t)k * PROWS * NPIX + n;
        #pragma unroll
        for (int r = 0; r < PROWS; r++) acc[r] += Pp[r * NPIX];
    }

    const float invS = 1.f / acc[21];
    const float invB = 1.f / acc[CPAD + 21];
    float spv[NC], blv[NC];
    #pragma unroll
    for (int c = 0; c < NC; c++) { spv[c] = acc[c] * invS; blv[c] = acc[CPAD + c] * invB; }

    float mp[NC];
    for (int o = 0; o < NC; o++) {
        float m = spb[o] + blb[o];
        #pragma unroll
        for (int c = 0; c < NC; c++)
            m += spw[o * NC + c] * spv[c] + blw[o * NC + c] * blv[c];
        mp[o] = m;
    }
    float q[NC];
    for (int o = 0; o < NC; o++) {
        float m = cpb[o];
        #pragma unroll
        for (int c = 0; c < NC; c++) m += cpw[o * NC + c] * mp[c];
        q[o] = u[n * CPAD + o] - m;
    }

    float mx = q[0];
    #pragma unroll
    for (int o = 1; o < NC; o++) mx = fmaxf(mx, q[o]);
    float e[NC], sum = 0.f;
    #pragma unroll
    for (int o = 0; o < NC; o++) { e[o] = __expf(q[o] - mx); sum += e[o]; }
    const float inv = 1.f / sum;
    #pragma unroll
    for (int o = 0; o < NC; o++) {
        const float sv = e[o] * inv;
        s[n * CPAD + o] = sv;
        if (write_out) out[o * NPIX + n] = sv;
    }
    s[n * CPAD + 21] = 1.f; s[n * CPAD + 22] = 0.f; s[n * CPAD + 23] = 0.f;
}

extern "C" void kernel_launch(void* const* d_in, const int* in_sizes, int n_in,
                              void* d_out, int out_size, void* d_ws, size_t ws_size,
                              hipStream_t stream) {
    const float* img    = (const float*)d_in[0];
    const float* net_w  = (const float*)d_in[1];
    const float* net_b  = (const float*)d_in[2];
    const float* sp_w   = (const float*)d_in[3];
    const float* sp_b   = (const float*)d_in[4];
    const float* bl_w   = (const float*)d_in[5];
    const float* bl_b   = (const float*)d_in[6];
    const float* comp_w = (const float*)d_in[7];
    const float* comp_b = (const float*)d_in[8];

    float* u     = (float*)d_ws;                 // NPIX*24
    float* s     = u + NPIX * CPAD;              // NPIX*24
    float* feats = s + NPIX * CPAD;              // NPIX*8
    float* P     = feats + NPIX * 8;             // msplit*48*NPIX

    const size_t fixed_bytes = (size_t)(NPIX * CPAD * 2 + NPIX * 8) * sizeof(float);
    int msplit = 16;
    while (msplit > 1 &&
           fixed_bytes + (size_t)msplit * PROWS * NPIX * sizeof(float) > ws_size)
        msplit >>= 1;
    const int chunkLen = NPIX / msplit;

    prep_kernel<<<dim3(NPIX / 256), dim3(256), 0, stream>>>(img, net_w, net_b, u, s, feats);
    for (int it = 0; it < NITER; it++) {
        filt_kernel<<<dim3(NPIX / 256, msplit), dim3(256), 0, stream>>>(s, feats, P, chunkLen);
        combine_kernel<<<dim3(NPIX / 256), dim3(256), 0, stream>>>(
            P, msplit, u, sp_w, sp_b, bl_w, bl_b, comp_w, comp_b,
            s, (float*)d_out, it == NITER - 1 ? 1 : 0);
    }
}

// Round 3
// 443.624 us; speedup vs baseline: 3.2145x; 3.2145x over previous
//
#include <hip/hip_runtime.h>

#define NPIX 9216
#define IMH 96
#define IMW 96
#define NC 21
#define NCH 22          // 21 classes + norm channel (all-ones)
#define NMON 252        // monomials of degree <=5 in 5 vars
#define RAD 15          // spatial Gaussian truncation radius (sigma=3)
#define NITER 5

// Taylor coeffs of exp(t) ~ e^c * sum a_k t^k around c=0.52 (degree 5)
__constant__ float d_ak[6] = {0.59449500f, 0.59481184f, 0.29588267f,
                              0.10253333f, 0.02f, 0.00833333f};

__device__ __forceinline__ float gw(int d) {
    return __expf((float)(d * d) * (-1.0f / 18.0f));  // spatial tap, sigma=3
}

// ---------------- prep: unary conv + softmax + monomial features ----------------
__global__ __launch_bounds__(256) void prep_kernel(
    const float* __restrict__ img, const float* __restrict__ net_w,
    const float* __restrict__ net_b,
    float* __restrict__ u, float* __restrict__ s,
    float* __restrict__ phi, float* __restrict__ gam)
{
    __shared__ float wsh[567], bsh[21];
    const int tid = threadIdx.x;
    for (int i = tid; i < 567; i += 256) wsh[i] = net_w[i];
    if (tid < 21) bsh[tid] = net_b[tid];
    __syncthreads();

    const int n = blockIdx.x * 256 + tid;
    const int i = n / IMW, j = n % IMW;

    float acc[NC];
    #pragma unroll
    for (int o = 0; o < NC; o++) acc[o] = bsh[o];
    for (int ci = 0; ci < 3; ci++)
        for (int ky = 0; ky < 3; ky++)
            for (int kx = 0; kx < 3; kx++) {
                const int ii = i + ky - 1, jj = j + kx - 1;
                float v = 0.f;
                if (ii >= 0 && ii < IMH && jj >= 0 && jj < IMW)
                    v = img[(ci * IMH + ii) * IMW + jj];
                #pragma unroll
                for (int o = 0; o < NC; o++)
                    acc[o] = fmaf(v, wsh[((o * 3 + ci) * 3 + ky) * 3 + kx], acc[o]);
            }

    float mx = acc[0];
    #pragma unroll
    for (int o = 1; o < NC; o++) mx = fmaxf(mx, acc[o]);
    float e[NC], sum = 0.f;
    #pragma unroll
    for (int o = 0; o < NC; o++) { e[o] = __expf(acc[o] - mx); sum += e[o]; }
    const float inv = 1.f / sum;
    #pragma unroll
    for (int o = 0; o < NC; o++) {
        u[o * NPIX + n] = acc[o];
        s[o * NPIX + n] = e[o] * inv;
    }
    s[21 * NPIX + n] = 1.f;   // norm channel

    // bilateral features, scaled: alpha=160 (pos), beta=3 (color)
    const float f1 = (float)j * (1.0f / 160.0f);
    const float f2 = (float)i * (1.0f / 160.0f);
    const float f3 = img[0 * NPIX + n] * (1.0f / 3.0f);
    const float f4 = img[1 * NPIX + n] * (1.0f / 3.0f);
    const float f5 = img[2 * NPIX + n] * (1.0f / 3.0f);
    const float env = __expf(-0.5f * (f1 * f1 + f2 * f2 + f3 * f3 + f4 * f4 + f5 * f5));

    // phi[m][n] = env * f^m, lexicographic over (d1..d5), sum<=5 -> 252 rows
    int idx = 0;
    float a1 = env;
    for (int d1 = 0; d1 <= 5; d1++) {
        float a2 = a1;
        for (int d2 = 0; d2 <= 5 - d1; d2++) {
            float a3 = a2;
            for (int d3 = 0; d3 <= 5 - d1 - d2; d3++) {
                float a4 = a3;
                for (int d4 = 0; d4 <= 5 - d1 - d2 - d3; d4++) {
                    float a5 = a4;
                    for (int d5 = 0; d5 <= 5 - d1 - d2 - d3 - d4; d5++) {
                        phi[(size_t)idx * NPIX + n] = a5;
                        idx++;
                        a5 *= f5;
                    }
                    a4 *= f4;
                }
                a3 *= f3;
            }
            a2 *= f2;
        }
        a1 *= f1;
    }

    // gamma table (one thread): gamma_m = a_k * k!/(d1!..d5!), k=|m|
    if (blockIdx.x == 0 && tid == 0) {
        const float fact[6] = {1.f, 1.f, 2.f, 6.f, 24.f, 120.f};
        int gi = 0;
        for (int d1 = 0; d1 <= 5; d1++)
            for (int d2 = 0; d2 <= 5 - d1; d2++)
                for (int d3 = 0; d3 <= 5 - d1 - d2; d3++)
                    for (int d4 = 0; d4 <= 5 - d1 - d2 - d3; d4++)
                        for (int d5 = 0; d5 <= 5 - d1 - d2 - d3 - d4; d5++) {
                            int k = d1 + d2 + d3 + d4 + d5;
                            gam[gi++] = d_ak[k] * fact[k] /
                                (fact[d1] * fact[d2] * fact[d3] * fact[d4] * fact[d5]);
                        }
    }
}

// ---------------- K1: spatial conv x-pass  ||  bilateral stage1 GEMM ----------------
__global__ __launch_bounds__(256) void k1_kernel(
    const float* __restrict__ s, const float* __restrict__ phi,
    float* __restrict__ sx, float* __restrict__ M)
{
    const int tid = threadIdx.x;
    if (blockIdx.x < NCH * 36) {
        const int ch = blockIdx.x / 36;
        const int n = (blockIdx.x % 36) * 256 + tid;
        const int i = n / IMW, j = n % IMW;
        const float* row = s + (size_t)ch * NPIX + i * IMW;
        float acc = 0.f;
        #pragma unroll
        for (int d = -RAD; d <= RAD; d++) {
            const int jj = j + d;
            if (jj >= 0 && jj < IMW) acc = fmaf(gw(d), row[jj], acc);
        }
        sx[(size_t)ch * NPIX + n] = acc;
    } else {
        // stage1: M[m][ch] = sum_n phi[m][n] * s[ch][n]
        const int m = blockIdx.x - NCH * 36;
        __shared__ float red[4 * NCH];
        const float4* ph4 = (const float4*)(phi + (size_t)m * NPIX);
        float acc[NCH];
        #pragma unroll
        for (int c = 0; c < NCH; c++) acc[c] = 0.f;
        for (int rep = 0; rep < 9; rep++) {
            const int n4 = rep * 256 + tid;
            const float4 p = ph4[n4];
            #pragma unroll
            for (int c = 0; c < NCH; c++) {
                const float4 sv = ((const float4*)(s + (size_t)c * NPIX))[n4];
                acc[c] += p.x * sv.x + p.y * sv.y + p.z * sv.z + p.w * sv.w;
            }
        }
        const int lane = tid & 63, wv = tid >> 6;
        #pragma unroll
        for (int c = 0; c < NCH; c++) {
            float v = acc[c];
            for (int off = 32; off > 0; off >>= 1) v += __shfl_down(v, off, 64);
            if (lane == 0) red[wv * NCH + c] = v;
        }
        __syncthreads();
        if (tid < NCH)
            M[m * NCH + tid] =
                red[tid] + red[NCH + tid] + red[2 * NCH + tid] + red[3 * NCH + tid];
    }
}

// ---------------- K2: spatial conv y-pass  ||  bilateral stage2 GEMM ----------------
__global__ __launch_bounds__(256) void k2_kernel(
    const float* __restrict__ sx, const float* __restrict__ phi,
    const float* __restrict__ M, const float* __restrict__ gam,
    float* __restrict__ sp, float* __restrict__ blp, int msz)
{
    const int tid = threadIdx.x;
    if (blockIdx.x < NCH * 36) {
        const int ch = blockIdx.x / 36;
        const int n = (blockIdx.x % 36) * 256 + tid;
        const int i = n / IMW, j = n % IMW;
        const float* plane = sx + (size_t)ch * NPIX;
        float acc = 0.f;
        #pragma unroll
        for (int d = -RAD; d <= RAD; d++) {
            const int ii = i + d;
            if (ii >= 0 && ii < IMH) acc = fmaf(gw(d), plane[ii * IMW + j], acc);
        }
        sp[(size_t)ch * NPIX + n] = acc;
    } else {
        const int t = blockIdx.x - NCH * 36;
        const int mc = t / 36, pb = t % 36;
        const int n = pb * 256 + tid;
        __shared__ float Msh[NMON * NCH];
        __shared__ float gsh[NMON];
        const int m0 = mc * msz;
        for (int i2 = tid; i2 < msz * NCH; i2 += 256) Msh[i2] = M[m0 * NCH + i2];
        for (int i2 = tid; i2 < msz; i2 += 256) gsh[i2] = gam[m0 + i2];
        __syncthreads();
        float acc[NCH];
        #pragma unroll
        for (int c = 0; c < NCH; c++) acc[c] = 0.f;
        for (int mm = 0; mm < msz; mm++) {
            const float p = gsh[mm] * phi[(size_t)(m0 + mm) * NPIX + n];
            #pragma unroll
            for (int c = 0; c < NCH; c++) acc[c] = fmaf(p, Msh[mm * NCH + c], acc[c]);
        }
        #pragma unroll
        for (int c = 0; c < NCH; c++)
            blp[((size_t)mc * NCH + c) * NPIX + n] = acc[c];
    }
}

// ---------------- K3: normalize + compat transform + softmax ----------------
__global__ __launch_bounds__(256) void k3_kernel(
    const float* __restrict__ sp, const float* __restrict__ blp, int nmc,
    const float* __restrict__ u,
    const float* __restrict__ sp_w, const float* __restrict__ sp_b,
    const float* __restrict__ bl_w, const float* __restrict__ bl_b,
    const float* __restrict__ comp_w, const float* __restrict__ comp_b,
    float* __restrict__ s, float* __restrict__ out, int write_out)
{
    __shared__ float spw[441], blw[441], cpw[441], spb[21], blb[21], cpb[21];
    const int tid = threadIdx.x;
    for (int i = tid; i < 441; i += 256) {
        spw[i] = sp_w[i]; blw[i] = bl_w[i]; cpw[i] = comp_w[i];
    }
    if (tid < 21) { spb[tid] = sp_b[tid]; blb[tid] = bl_b[tid]; cpb[tid] = comp_b[tid]; }
    __syncthreads();

    const int n = blockIdx.x * 256 + tid;

    float spv[NCH], blv[NCH];
    #pragma unroll
    for (int c = 0; c < NCH; c++) { spv[c] = sp[(size_t)c * NPIX + n]; blv[c] = 0.f; }
    for (int mc = 0; mc < nmc; mc++) {
        #pragma unroll
        for (int c = 0; c < NCH; c++)
            blv[c] += blp[((size_t)mc * NCH + c) * NPIX + n];
    }
    const float invS = 1.f / spv[21];
    const float invB = 1.f / blv[21];
    #pragma unroll
    for (int c = 0; c < NC; c++) { spv[c] *= invS; blv[c] *= invB; }

    float mp[NC];
    for (int o = 0; o < NC; o++) {
        float m = spb[o] + blb[o];
        #pragma unroll
        for (int c = 0; c < NC; c++)
            m += spw[o * NC + c] * spv[c] + blw[o * NC + c] * blv[c];
        mp[o] = m;
    }
    float q[NC];
    for (int o = 0; o < NC; o++) {
        float m = cpb[o];
        #pragma unroll
        for (int c = 0; c < NC; c++) m += cpw[o * NC + c] * mp[c];
        q[o] = u[(size_t)o * NPIX + n] - m;
    }

    float mx = q[0];
    #pragma unroll
    for (int o = 1; o < NC; o++) mx = fmaxf(mx, q[o]);
    float e[NC], sum = 0.f;
    #pragma unroll
    for (int o = 0; o < NC; o++) { e[o] = __expf(q[o] - mx); sum += e[o]; }
    const float inv = 1.f / sum;
    #pragma unroll
    for (int o = 0; o < NC; o++) {
        const float sv = e[o] * inv;
        s[(size_t)o * NPIX + n] = sv;
        if (write_out) out[(size_t)o * NPIX + n] = sv;
    }
    s[21 * NPIX + n] = 1.f;
}

extern "C" void kernel_launch(void* const* d_in, const int* in_sizes, int n_in,
                              void* d_out, int out_size, void* d_ws, size_t ws_size,
                              hipStream_t stream) {
    const float* img    = (const float*)d_in[0];
    const float* net_w  = (const float*)d_in[1];
    const float* net_b  = (const float*)d_in[2];
    const float* sp_w   = (const float*)d_in[3];
    const float* sp_b   = (const float*)d_in[4];
    const float* bl_w   = (const float*)d_in[5];
    const float* bl_b   = (const float*)d_in[6];
    const float* comp_w = (const float*)d_in[7];
    const float* comp_b = (const float*)d_in[8];

    float* s   = (float*)d_ws;                 // [22][NPIX]
    float* u   = s + (size_t)NCH * NPIX;       // [21][NPIX] (alloc 22)
    float* sx  = u + (size_t)NCH * NPIX;       // [22][NPIX]
    float* sp  = sx + (size_t)NCH * NPIX;      // [22][NPIX]
    float* phi = sp + (size_t)NCH * NPIX;      // [252][NPIX]
    float* M   = phi + (size_t)NMON * NPIX;    // [252][22] (pad 5632)
    float* gam = M + 5632;                     // [252] (pad 256)
    float* blp = gam + 256;                    // [nmc][22][NPIX]

    const size_t fixed = (size_t)(blp - (float*)d_ws);
    static const int chain[6] = {12, 6, 4, 3, 2, 1};
    int nmc = 1;
    for (int ci = 0; ci < 6; ci++) {
        if ((fixed + (size_t)chain[ci] * NCH * NPIX) * sizeof(float) <= ws_size) {
            nmc = chain[ci]; break;
        }
    }
    const int msz = NMON / nmc;

    prep_kernel<<<dim3(36), dim3(256), 0, stream>>>(img, net_w, net_b, u, s, phi, gam);
    for (int it = 0; it < NITER; it++) {
        k1_kernel<<<dim3(NCH * 36 + NMON), dim3(256), 0, stream>>>(s, phi, sx, M);
        k2_kernel<<<dim3(NCH * 36 + 36 * nmc), dim3(256), 0, stream>>>(
            sx, phi, M, gam, sp, blp, msz);
        k3_kernel<<<dim3(36), dim3(256), 0, stream>>>(
            sp, blp, nmc, u, sp_w, sp_b, bl_w, bl_b, comp_w, comp_b,
            s, (float*)d_out, it == NITER - 1 ? 1 : 0);
    }
}